// Round 2
// baseline (1154.830 us; speedup 1.0000x reference)
//
#include <hip/hip_runtime.h>

typedef __bf16 bf16;
typedef __bf16 b16x8 __attribute__((ext_vector_type(8)));
typedef __bf16 b16x4 __attribute__((ext_vector_type(4)));
typedef float f32x4 __attribute__((ext_vector_type(4)));

#define TB 256
#define LDA 136          // LDS A-tile row stride (bf16): 2-way bank alias only (free)
#define NB 1024
#define NK 24
#define NE 552
#define NH 128
#define BEcnt (NB*NE)    // 565248
#define BNODE (NB*NK)    // 24576
#define EPS 1e-5f

// ---- workspace layout ----
#define S_BN1 0          // [256] sum/sumsq
#define S_BN3 256
#define S_B2  512        // [32][256] bucketed
#define S_B4  8704
#define S_SC2 16896      // [256] BN2 scale/shift exported by k4a block 0
#define STATS_BYTES (17152*4)
#define OFF_H1  68608ull
#define OFF_H3  (OFF_H1 + 6291456ull)
#define OFF_Y2R (OFF_H3 + 6291456ull)
#define OFF_Y2S (OFF_Y2R + 12582912ull)
#define OFF_Y4R (OFF_Y2S + 12582912ull)
#define OFF_Y4S (OFF_Y4R + 12582912ull)
#define OFF_Z2  (OFF_Y4S + 12582912ull)
#define OFF_Z4  (OFF_Z2  + 12582912ull)   // total ~95 MB, h2 never materialized

__device__ __forceinline__ float elu(float x){ return x > 0.f ? x : __expf(x) - 1.f; }

// B-fragment: lane l holds W[n0 + (l&15)][k0 + (l>>4)*8 + j] (W row-major fp32 [out][in])
__device__ __forceinline__ b16x8 load_bfrag(const float* W, int ldw, int row, int kcol){
  const float* p = W + row*ldw + kcol;
  f32x4 v0 = *(const f32x4*)p;
  f32x4 v1 = *(const f32x4*)(p+4);
  b16x8 r;
  r[0]=(bf16)v0[0]; r[1]=(bf16)v0[1]; r[2]=(bf16)v0[2]; r[3]=(bf16)v0[3];
  r[4]=(bf16)v1[0]; r[5]=(bf16)v1[1]; r[6]=(bf16)v1[2]; r[7]=(bf16)v1[3];
  return r;
}

__device__ __forceinline__ void load_bfrags(const float* W, int ldw, int k0, b16x8 bfr[4][2], int lane, int w){
  int n = lane & 15, q = lane >> 4;
  #pragma unroll
  for (int kb=0; kb<4; ++kb)
    #pragma unroll
    for (int t=0; t<2; ++t)
      bfr[kb][t] = load_bfrag(W, ldw, (w*2+t)*16 + n, k0 + kb*32 + q*8);
}

__device__ __forceinline__ void gemm_regB(const bf16* As, const b16x8 bfr[4][2], f32x4 acc[6][2], int lane){
  int m = lane & 15, q = lane >> 4;
  #pragma unroll
  for (int kb=0; kb<4; ++kb){
    int ka = kb*32 + q*8;
    b16x8 a[6];
    #pragma unroll
    for (int mt=0; mt<6; ++mt)
      a[mt] = *(const b16x8*)(As + (mt*16+m)*LDA + ka);
    #pragma unroll
    for (int mt=0; mt<6; ++mt)
      #pragma unroll
      for (int t=0; t<2; ++t)
        acc[mt][t] = __builtin_amdgcn_mfma_f32_16x16x32_bf16(a[mt], bfr[kb][t], acc[mt][t], 0,0,0);
  }
}

__device__ __forceinline__ void zero_acc(f32x4 acc[6][2]){
  #pragma unroll
  for (int mt=0; mt<6; ++mt)
    #pragma unroll
    for (int t=0; t<2; ++t){ acc[mt][t][0]=0.f; acc[mt][t][1]=0.f; acc[mt][t][2]=0.f; acc[mt][t][3]=0.f; }
}

__device__ __forceinline__ void epilogue_to_lds(const f32x4 acc[6][2], const float* bias, bf16* As,
                                                int lane, int w, int validRows){
  int q = lane >> 4, n = lane & 15;
  #pragma unroll
  for (int mt=0; mt<6; ++mt)
    #pragma unroll
    for (int t=0; t<2; ++t){
      int col = (w*2+t)*16 + n;
      float bc = bias[col];
      #pragma unroll
      for (int i=0; i<4; ++i){
        int row = mt*16 + q*4 + i;
        float v = (row < validRows) ? elu(acc[mt][t][i] + bc) : 0.f;
        As[row*LDA + col] = (bf16)v;
      }
    }
}

__device__ __forceinline__ void write_acc_f32(const f32x4 acc[6][2], float* out, int lane, int w){
  int q = lane >> 4, n = lane & 15;
  #pragma unroll
  for (int mt=0; mt<6; ++mt)
    #pragma unroll
    for (int t=0; t<2; ++t){
      int col = (w*2+t)*16 + n;
      #pragma unroll
      for (int i=0; i<4; ++i)
        out[(mt*16 + q*4 + i)*NH + col] = acc[mt][t][i];
    }
}

__device__ __forceinline__ void store_and_stats(const bf16* As, bf16* g_out, float* statsDst,
                                                int tid, int validRows){
  for (int i = tid; i < validRows*16; i += TB){
    int row = i >> 4, c8 = (i & 15) << 3;
    *(b16x8*)(g_out + (size_t)row*NH + c8) = *(const b16x8*)(As + row*LDA + c8);
  }
  int c = tid & 127, half = tid >> 7;
  float s = 0.f, s2 = 0.f;
  for (int row = half; row < validRows; row += 2){
    float v = (float)As[row*LDA + c];
    s += v; s2 += v*v;
  }
  atomicAdd(&statsDst[c], s);
  atomicAdd(&statsDst[128+c], s2);
}

// Build A-tile: rows = edges e0..e0+91 (4 recv groups of 23), A = ELU(yr[r]+ys[s]+bias); pad rows 92..95 = 0
__device__ __forceinline__ void build_A(bf16* As, const float* ytr, const float* yts,
                                        const float* bias, int tile4, int tid){
  for (int i=tid; i<96*32; i+=TB){
    int row = i >> 5, c4 = (i & 31) << 2;
    b16x4 o;
    if (row < 92){
      int rl = (row>=23)+(row>=46)+(row>=69);
      int j = row - rl*23;
      int s = j + (j >= tile4 + rl);
      f32x4 vr = *(const f32x4*)(ytr + rl*NH + c4);
      f32x4 vs = *(const f32x4*)(yts + s*NH + c4);
      f32x4 bb = *(const f32x4*)(bias + c4);
      #pragma unroll
      for (int k=0; k<4; ++k) o[k] = (bf16)elu(vr[k]+vs[k]+bb[k]);
    } else {
      o[0]=o[1]=o[2]=o[3]=(bf16)0.f;
    }
    *(b16x4*)(As + row*LDA + c4) = o;
  }
}

// Register harvest: v = ELU(acc+bias) masked to valid rows; col-stats via shfl-reduce -> global
// bucket atomics; per-recv-group sums via LDS ds_add_f32 into zL[4][128]
__device__ __forceinline__ void harvest(const f32x4 acc[6][2], const float* bias,
                                        float* zL, float* statsDst, int lane, int w){
  int q4 = (lane >> 4) << 2, n = lane & 15;
  float s0=0.f, s1=0.f, p0=0.f, p1=0.f;
  int c0 = w*32 + n, c1 = w*32 + 16 + n;
  float b0 = bias[c0], b1 = bias[c1];
  #pragma unroll
  for (int mt=0; mt<6; ++mt){
    #pragma unroll
    for (int i=0; i<4; ++i){
      int row = mt*16 + q4 + i;
      int g = (row>=23)+(row>=46)+(row>=69);
      bool ok = row < 92;
      float* zr = zL + g*NH;
      float v0 = elu(acc[mt][0][i] + b0); v0 = ok ? v0 : 0.f;
      float v1 = elu(acc[mt][1][i] + b1); v1 = ok ? v1 : 0.f;
      s0 += v0; p0 += v0*v0;
      s1 += v1; p1 += v1*v1;
      atomicAdd(&zr[c0], v0);
      atomicAdd(&zr[c1], v1);
    }
  }
  s0 += __shfl_down(s0,32); s0 += __shfl_down(s0,16);
  s1 += __shfl_down(s1,32); s1 += __shfl_down(s1,16);
  p0 += __shfl_down(p0,32); p0 += __shfl_down(p0,16);
  p1 += __shfl_down(p1,32); p1 += __shfl_down(p1,16);
  if (lane < 16){
    atomicAdd(&statsDst[c0],    s0); atomicAdd(&statsDst[NH+c0], p0);
    atomicAdd(&statsDst[c1],    s1); atomicAdd(&statsDst[NH+c1], p1);
  }
}

// ---- K1: MLP1 (6->128 VALU, 128->128 MFMA) -> h1 (pre-BN, bf16) + BN1 stats ----
__global__ __launch_bounds__(TB) void k1_mlp1(const float* __restrict__ in,
    const float* __restrict__ w1, const float* __restrict__ b1,
    const float* __restrict__ w2, const float* __restrict__ b2,
    bf16* __restrict__ h1, float* __restrict__ bn1){
  __shared__ alignas(16) bf16 As[96*LDA];
  __shared__ float w1s[128*6];
  __shared__ float b1s[128], b2s[128];
  __shared__ float ins[96*6];
  int tid = threadIdx.x;
  int row0 = blockIdx.x * 96;
  for (int i=tid; i<768; i+=TB) w1s[i] = w1[i];
  if (tid < 128){ b1s[tid]=b1[tid]; b2s[tid]=b2[tid]; }
  for (int i=tid; i<576; i+=TB) ins[i] = in[row0*6 + i];
  __syncthreads();
  for (int i=tid; i<96*32; i+=TB){
    int row = i >> 5, c4 = (i & 31) << 2;
    float x0=ins[row*6+0], x1=ins[row*6+1], x2=ins[row*6+2],
          x3=ins[row*6+3], x4=ins[row*6+4], x5=ins[row*6+5];
    #pragma unroll
    for (int j=0; j<4; ++j){
      int c = c4 + j;
      const float* wr = w1s + c*6;
      float s = b1s[c] + wr[0]*x0 + wr[1]*x1 + wr[2]*x2 + wr[3]*x3 + wr[4]*x4 + wr[5]*x5;
      As[row*LDA + c] = (bf16)elu(s);
    }
  }
  int lane = tid & 63, w = tid >> 6;
  b16x8 bfr[4][2];
  load_bfrags(w2, 128, 0, bfr, lane, w);
  __syncthreads();
  f32x4 acc[6][2]; zero_acc(acc);
  gemm_regB(As, bfr, acc, lane);
  __syncthreads();
  epilogue_to_lds(acc, b2s, As, lane, w, 96);
  __syncthreads();
  store_and_stats(As, h1 + (size_t)row0*NH, bn1, tid, 96);
}

// ---- K2/K4b: fold BN affine into h, project yr = W[:, :128]@x, ys = W[:,128:256]@x per node ----
__global__ __launch_bounds__(TB) void k_project(const bf16* __restrict__ hin,
    const float* __restrict__ stats, float cnt,
    const float* __restrict__ g, const float* __restrict__ be,
    const float* __restrict__ Wp, int ldw,
    float* __restrict__ yr, float* __restrict__ ys){
  __shared__ alignas(16) bf16 As[96*LDA];
  __shared__ float scl[128], shf[128];
  int tid = threadIdx.x;
  int row0 = blockIdx.x * 96;
  if (tid < 128){
    float mean = stats[tid] / cnt;
    float var  = stats[128+tid] / cnt - mean*mean;
    float rs = rsqrtf(var + EPS);
    float sc = g[tid] * rs;
    scl[tid] = sc; shf[tid] = be[tid] - mean*sc;
  }
  __syncthreads();
  for (int i=tid; i<96*16; i+=TB){
    int row = i >> 4, c8 = (i & 15) << 3;
    b16x8 v = *(const b16x8*)(hin + (size_t)(row0+row)*NH + c8);
    b16x8 o;
    #pragma unroll
    for (int j=0; j<8; ++j) o[j] = (bf16)(scl[c8+j]*(float)v[j] + shf[c8+j]);
    *(b16x8*)(As + row*LDA + c8) = o;
  }
  int lane = tid & 63, w = tid >> 6;
  b16x8 bfr[4][2];
  load_bfrags(Wp, ldw, 0, bfr, lane, w);
  __syncthreads();
  f32x4 acc[6][2]; zero_acc(acc);
  gemm_regB(As, bfr, acc, lane);
  write_acc_f32(acc, yr + (size_t)row0*NH, lane, w);
  load_bfrags(Wp, ldw, 128, bfr, lane, w);
  zero_acc(acc);
  gemm_regB(As, bfr, acc, lane);
  write_acc_f32(acc, ys + (size_t)row0*NH, lane, w);
}

// ---- K3: per-edge MLP2, NO h2 store: A=ELU(y2r[r]+y2s[s]+b21), GEMM W22, harvest BN2 stats + z2 sums ----
__global__ __launch_bounds__(TB,3) void k3_edge1(const float* __restrict__ y2r, const float* __restrict__ y2s,
    const float* __restrict__ b21, const float* __restrict__ w22, const float* __restrict__ b22,
    float* __restrict__ z2, float* __restrict__ bn2buck){
  __shared__ alignas(16) bf16 As[96*LDA];
  __shared__ alignas(16) float ytab[3584];   // [4][128] recv rows + [24][128] send rows
  __shared__ float b1s[NH], b2s[NH], zL[512];
  int tid = threadIdx.x;
  int b = blockIdx.x / 6, tile = blockIdx.x % 6, tile4 = tile*4;
  {
    const f32x4* yrB = (const f32x4*)(y2r + ((size_t)b*NK + tile4)*NH);
    const f32x4* ysB = (const f32x4*)(y2s + (size_t)b*NK*NH);
    for (int i=tid; i<896; i+=TB){
      const f32x4* p = (i < 128) ? (yrB + i) : (ysB + (i-128));
      ((f32x4*)ytab)[i] = *p;
    }
  }
  if (tid < NH){ b1s[tid]=b21[tid]; b2s[tid]=b22[tid]; }
  for (int i=tid; i<512; i+=TB) zL[i] = 0.f;
  int lane = tid & 63, w = tid >> 6;
  b16x8 bfr[4][2];
  load_bfrags(w22, 128, 0, bfr, lane, w);
  __syncthreads();
  build_A(As, ytab, ytab+512, b1s, tile4, tid);
  __syncthreads();
  f32x4 acc[6][2]; zero_acc(acc);
  gemm_regB(As, bfr, acc, lane);
  harvest(acc, b2s, zL, bn2buck + (blockIdx.x & 31)*256, lane, w);
  __syncthreads();
  float* zdst = z2 + (size_t)(b*NK + tile4)*NH;
  for (int i=tid; i<512; i+=TB) zdst[i] = zL[i];
}

// ---- K4a: finalize BN2 from buckets; MLP3 on normalized edge2node(z2); h3 + BN3 stats; export BN2 affine ----
__global__ __launch_bounds__(TB) void k4a_mlp3(const float* __restrict__ z2,
    const float* __restrict__ bn2buck, const float* __restrict__ g2, const float* __restrict__ be2,
    const float* __restrict__ w31, const float* __restrict__ b31,
    const float* __restrict__ w32, const float* __restrict__ b32,
    bf16* __restrict__ h3, float* __restrict__ bn3, float* __restrict__ sc2out){
  __shared__ alignas(16) bf16 As[96*LDA];
  __shared__ float scl[128], shf[128], b1s[128], b2s[128];
  __shared__ float sred[256];
  int tid = threadIdx.x;
  int row0 = blockIdx.x * 96;
  {
    int c = tid & 127, part = tid >> 7;
    float s = 0.f;
    for (int i=0; i<32; ++i) s += bn2buck[i*256 + part*128 + c];
    sred[tid] = s;
  }
  if (tid < 128){ b1s[tid]=b31[tid]; b2s[tid]=b32[tid]; }
  __syncthreads();
  if (tid < 128){
    float mean = sred[tid] / (float)BEcnt;
    float var  = sred[128+tid] / (float)BEcnt - mean*mean;
    float rs = rsqrtf(var + EPS);
    float sc = g2[tid] * rs;
    float sh = be2[tid] - mean*sc;
    scl[tid] = sc * (1.f/24.f);
    shf[tid] = sh * (23.f/24.f);
    if (blockIdx.x == 0){ sc2out[tid] = sc; sc2out[128+tid] = sh; }
  }
  __syncthreads();
  for (int i=tid; i<96*32; i+=TB){
    int rl = i >> 5, c4 = (i & 31) << 2;
    f32x4 v = *(const f32x4*)(z2 + (size_t)(row0+rl)*NH + c4);
    b16x4 o;
    #pragma unroll
    for (int k=0; k<4; ++k) o[k] = (bf16)(scl[c4+k]*v[k] + shf[c4+k]);
    *(b16x4*)(As + rl*LDA + c4) = o;
  }
  int lane = tid & 63, w = tid >> 6;
  b16x8 bfr[4][2];
  load_bfrags(w31, 128, 0, bfr, lane, w);
  __syncthreads();
  f32x4 acc[6][2]; zero_acc(acc);
  gemm_regB(As, bfr, acc, lane);
  __syncthreads();
  epilogue_to_lds(acc, b1s, As, lane, w, 96);
  load_bfrags(w32, 128, 0, bfr, lane, w);
  __syncthreads();
  zero_acc(acc);
  gemm_regB(As, bfr, acc, lane);
  __syncthreads();
  epilogue_to_lds(acc, b2s, As, lane, w, 96);
  __syncthreads();
  store_and_stats(As, h3 + (size_t)row0*NH, bn3, tid, 96);
}

// ---- K5: per-edge MLP4 with h2 RECOMPUTE (no global h2): 3 GEMMs; harvest BN4 stats + z4 ----
__global__ __launch_bounds__(TB,3) void k5_edge2(
    const float* __restrict__ y2r, const float* __restrict__ y2s,
    const float* __restrict__ y4r, const float* __restrict__ y4s,
    const float* __restrict__ sc2,
    const float* __restrict__ b21, const float* __restrict__ w22, const float* __restrict__ b22,
    const float* __restrict__ w41, const float* __restrict__ b41,
    const float* __restrict__ w42, const float* __restrict__ b42,
    float* __restrict__ z4, float* __restrict__ bn4buck){
  __shared__ alignas(16) bf16 As[96*LDA];
  __shared__ alignas(16) float ytab[3584];
  __shared__ float b21s[NH], b22s[NH], scl[NH], shf[NH], b41s[NH], b42s[NH], zL[512];
  int tid = threadIdx.x;
  int b = blockIdx.x / 6, tile = blockIdx.x % 6, tile4 = tile*4;
  {
    const f32x4* yrB = (const f32x4*)(y2r + ((size_t)b*NK + tile4)*NH);
    const f32x4* ysB = (const f32x4*)(y2s + (size_t)b*NK*NH);
    for (int i=tid; i<896; i+=TB){
      const f32x4* p = (i < 128) ? (yrB + i) : (ysB + (i-128));
      ((f32x4*)ytab)[i] = *p;
    }
  }
  if (tid < NH){
    b21s[tid]=b21[tid]; b22s[tid]=b22[tid];
    scl[tid]=sc2[tid];  shf[tid]=sc2[NH+tid];
    b41s[tid]=b41[tid]; b42s[tid]=b42[tid];
  }
  for (int i=tid; i<512; i+=TB) zL[i] = 0.f;
  int lane = tid & 63, w = tid >> 6;
  b16x8 bfr[4][2];
  load_bfrags(w22, 128, 0, bfr, lane, w);
  __syncthreads();
  build_A(As, ytab, ytab+512, b21s, tile4, tid);    // A2 = ELU(y2r[r]+y2s[s]+b21)
  __syncthreads();
  // prefetch y4 tables into regs (overlaps GEMM W22)
  f32x4 t4[4];
  {
    const f32x4* yrB = (const f32x4*)(y4r + ((size_t)b*NK + tile4)*NH);
    const f32x4* ysB = (const f32x4*)(y4s + (size_t)b*NK*NH);
    #pragma unroll
    for (int k2=0; k2<4; ++k2){
      int i = tid + k2*TB;
      if (i < 896){
        const f32x4* p = (i < 128) ? (yrB + i) : (ysB + (i-128));
        t4[k2] = *p;
      }
    }
  }
  f32x4 acc[6][2]; zero_acc(acc);
  gemm_regB(As, bfr, acc, lane);                    // h2 pre-act = W22 @ A2
  load_bfrags(w41, 384, 256, bfr, lane, w);         // skip third of m4_w1
  __syncthreads();                                  // all waves done reading As
  // epi1: h2n = sc2*ELU(h2+b22)+sh2 -> As
  {
    int q = lane >> 4, n = lane & 15;
    #pragma unroll
    for (int mt=0; mt<6; ++mt)
      #pragma unroll
      for (int t=0; t<2; ++t){
        int col = w*32 + t*16 + n;
        float bc = b22s[col], sc = scl[col], sh = shf[col];
        #pragma unroll
        for (int i=0; i<4; ++i){
          int row = mt*16 + q*4 + i;
          float h = elu(acc[mt][t][i] + bc);
          As[row*LDA + col] = (bf16)(sc*h + sh);
        }
      }
  }
  // stash y4 tables to LDS (ytab's y2 contents dead since build_A)
  #pragma unroll
  for (int k2=0; k2<4; ++k2){
    int i = tid + k2*TB;
    if (i < 896) ((f32x4*)ytab)[i] = t4[k2];
  }
  zero_acc(acc);
  __syncthreads();                                  // As(h2n) + ytab(y4) ready
  gemm_regB(As, bfr, acc, lane);                    // skip = W41c @ h2n
  load_bfrags(w42, 128, 0, bfr, lane, w);
  __syncthreads();                                  // done reading As(h2n)
  // epi2: A4 = ELU(skip + y4r[r] + y4s[s] + b41) -> As (pad rows zeroed)
  {
    int q4v = (lane >> 4) << 2, n = lane & 15;
    const float* ytr4 = ytab;
    const float* yts4 = ytab + 512;
    #pragma unroll
    for (int mt=0; mt<6; ++mt)
      #pragma unroll
      for (int i=0; i<4; ++i){
        int row = mt*16 + q4v + i;
        bool ok = row < 92;
        int rl = (row>=23)+(row>=46)+(row>=69);
        int j = row - rl*23;
        int s = j + (j >= tile4 + rl);
        #pragma unroll
        for (int t=0; t<2; ++t){
          int col = w*32 + t*16 + n;
          float v = 0.f;
          if (ok) v = elu(acc[mt][t][i] + ytr4[rl*NH+col] + yts4[s*NH+col] + b41s[col]);
          As[row*LDA + col] = (bf16)v;
        }
      }
  }
  zero_acc(acc);
  __syncthreads();
  gemm_regB(As, bfr, acc, lane);                    // h4 pre-act = W42 @ A4
  harvest(acc, b42s, zL, bn4buck + (blockIdx.x & 31)*256, lane, w);
  __syncthreads();
  float* zdst = z4 + (size_t)(b*NK + tile4)*NH;
  for (int i=tid; i<512; i+=TB) zdst[i] = zL[i];
}

// ---- K6: finalize BN4, apply affine to z4 sums, final 3072->2 projection ----
__global__ __launch_bounds__(TB) void k6_out(const float* __restrict__ z4,
    const float* __restrict__ bn4buck, const float* __restrict__ g4, const float* __restrict__ be4,
    const float* __restrict__ fo_w, const float* __restrict__ fo_b, float* __restrict__ out){
  __shared__ float red[512];
  __shared__ float scl[128], shf[128];
  int tid = threadIdx.x, b = blockIdx.x;
  {
    int c = tid & 127, part = tid >> 7;
    float s = 0.f;
    for (int i=0; i<32; ++i) s += bn4buck[i*256 + part*128 + c];
    red[tid] = s;
  }
  __syncthreads();
  if (tid < 128){
    float mean = red[tid] / (float)BEcnt;
    float var  = red[128+tid] / (float)BEcnt - mean*mean;
    float rs = rsqrtf(var + EPS);
    float sc = g4[tid] * rs;
    scl[tid] = sc; shf[tid] = be4[tid] - mean*sc;
  }
  __syncthreads();
  const float inv24 = 1.f/24.f, f2324 = 23.f/24.f;
  float a0 = 0.f, a1 = 0.f;
  for (int i=tid; i<3072; i+=TB){
    int c = i & 127;
    float x = scl[c]*z4[(size_t)b*3072 + i]*inv24 + shf[c]*f2324;
    a0 += x * fo_w[i];
    a1 += x * fo_w[3072 + i];
  }
  red[tid] = a0; red[256+tid] = a1;
  __syncthreads();
  for (int st=128; st>0; st>>=1){
    if (tid < st){ red[tid] += red[tid+st]; red[256+tid] += red[256+tid+st]; }
    __syncthreads();
  }
  if (tid == 0){
    out[b*2+0] = red[0] + fo_b[0];
    out[b*2+1] = red[256] + fo_b[1];
  }
}

extern "C" void kernel_launch(void* const* d_in, const int* in_sizes, int n_in,
                              void* d_out, int out_size, void* d_ws, size_t ws_size,
                              hipStream_t stream){
  (void)in_sizes; (void)n_in; (void)out_size; (void)ws_size;
  const float* inputs = (const float*)d_in[0];
  const float* fo_w  = (const float*)d_in[3];
  const float* fo_b  = (const float*)d_in[4];
  const float* m1_w1=(const float*)d_in[5];  const float* m1_b1=(const float*)d_in[6];
  const float* m1_w2=(const float*)d_in[7];  const float* m1_b2=(const float*)d_in[8];
  const float* m1_g =(const float*)d_in[9];  const float* m1_be=(const float*)d_in[10];
  const float* m2_w1=(const float*)d_in[11]; const float* m2_b1=(const float*)d_in[12];
  const float* m2_w2=(const float*)d_in[13]; const float* m2_b2=(const float*)d_in[14];
  const float* m2_g =(const float*)d_in[15]; const float* m2_be=(const float*)d_in[16];
  const float* m3_w1=(const float*)d_in[17]; const float* m3_b1=(const float*)d_in[18];
  const float* m3_w2=(const float*)d_in[19]; const float* m3_b2=(const float*)d_in[20];
  const float* m3_g =(const float*)d_in[21]; const float* m3_be=(const float*)d_in[22];
  const float* m4_w1=(const float*)d_in[23]; const float* m4_b1=(const float*)d_in[24];
  const float* m4_w2=(const float*)d_in[25]; const float* m4_b2=(const float*)d_in[26];
  const float* m4_g =(const float*)d_in[27]; const float* m4_be=(const float*)d_in[28];

  char* ws = (char*)d_ws;
  float* stats = (float*)ws;
  bf16* h1  = (bf16*)(ws + OFF_H1);
  bf16* h3  = (bf16*)(ws + OFF_H3);
  float* y2r = (float*)(ws + OFF_Y2R);
  float* y2s = (float*)(ws + OFF_Y2S);
  float* y4r = (float*)(ws + OFF_Y4R);
  float* y4s = (float*)(ws + OFF_Y4S);
  float* z2  = (float*)(ws + OFF_Z2);
  float* z4  = (float*)(ws + OFF_Z4);
  float* out = (float*)d_out;

  (void)hipMemsetAsync(d_ws, 0, STATS_BYTES, stream);
  k1_mlp1<<<256, TB, 0, stream>>>(inputs, m1_w1, m1_b1, m1_w2, m1_b2, h1, stats + S_BN1);
  k_project<<<256, TB, 0, stream>>>(h1, stats + S_BN1, (float)BNODE, m1_g, m1_be, m2_w1, 256, y2r, y2s);
  k3_edge1<<<6144, TB, 0, stream>>>(y2r, y2s, m2_b1, m2_w2, m2_b2, z2, stats + S_B2);
  k4a_mlp3<<<256, TB, 0, stream>>>(z2, stats + S_B2, m2_g, m2_be, m3_w1, m3_b1, m3_w2, m3_b2,
                                   h3, stats + S_BN3, stats + S_SC2);
  k_project<<<256, TB, 0, stream>>>(h3, stats + S_BN3, (float)BNODE, m3_g, m3_be, m4_w1, 384, y4r, y4s);
  k5_edge2<<<6144, TB, 0, stream>>>(y2r, y2s, y4r, y4s, stats + S_SC2,
                                    m2_b1, m2_w2, m2_b2, m4_w1, m4_b1, m4_w2, m4_b2,
                                    z4, stats + S_B4);
  k6_out<<<1024, TB, 0, stream>>>(z4, stats + S_B4, m4_g, m4_be, fo_w, fo_b, out);
}

// Round 3
// 479.125 us; speedup vs baseline: 2.4103x; 2.4103x over previous
//
#include <hip/hip_runtime.h>

typedef __bf16 bf16;
typedef __bf16 b16x8 __attribute__((ext_vector_type(8)));
typedef __bf16 b16x4 __attribute__((ext_vector_type(4)));
typedef float f32x4 __attribute__((ext_vector_type(4)));

#define TB 256
#define LDA 136          // LDS A-tile row stride (bf16): 2-way bank alias only (free)
#define NB 1024
#define NK 24
#define NE 552
#define NH 128
#define BEcnt (NB*NE)    // 565248
#define BNODE (NB*NK)    // 24576
#define EPS 1e-5f

// ---- workspace layout ----
#define S_BN1 0          // [256] sum/sumsq
#define S_BN3 256
#define S_B2  512        // [32][256] bucketed
#define S_B4  8704
#define S_SC2 16896      // [256] BN2 scale/shift exported by k4a block 0
#define STATS_BYTES (17152*4)
#define OFF_H1  68608ull
#define OFF_H3  (OFF_H1 + 6291456ull)
#define OFF_Y2R (OFF_H3 + 6291456ull)
#define OFF_Y2S (OFF_Y2R + 12582912ull)
#define OFF_Y4R (OFF_Y2S + 12582912ull)
#define OFF_Y4S (OFF_Y4R + 12582912ull)
#define OFF_Z2  (OFF_Y4S + 12582912ull)
#define OFF_Z4  (OFF_Z2  + 12582912ull)   // total ~95 MB, h2 never materialized

__device__ __forceinline__ float elu(float x){ return x > 0.f ? x : __expf(x) - 1.f; }

// B-fragment: lane l holds W[n0 + (l&15)][k0 + (l>>4)*8 + j] (W row-major fp32 [out][in])
__device__ __forceinline__ b16x8 load_bfrag(const float* W, int ldw, int row, int kcol){
  const float* p = W + row*ldw + kcol;
  f32x4 v0 = *(const f32x4*)p;
  f32x4 v1 = *(const f32x4*)(p+4);
  b16x8 r;
  r[0]=(bf16)v0[0]; r[1]=(bf16)v0[1]; r[2]=(bf16)v0[2]; r[3]=(bf16)v0[3];
  r[4]=(bf16)v1[0]; r[5]=(bf16)v1[1]; r[6]=(bf16)v1[2]; r[7]=(bf16)v1[3];
  return r;
}

__device__ __forceinline__ void load_bfrags(const float* W, int ldw, int k0, b16x8 bfr[4][2], int lane, int w){
  int n = lane & 15, q = lane >> 4;
  #pragma unroll
  for (int kb=0; kb<4; ++kb)
    #pragma unroll
    for (int t=0; t<2; ++t)
      bfr[kb][t] = load_bfrag(W, ldw, (w*2+t)*16 + n, k0 + kb*32 + q*8);
}

__device__ __forceinline__ void gemm_regB(const bf16* As, const b16x8 bfr[4][2], f32x4 acc[6][2], int lane){
  int m = lane & 15, q = lane >> 4;
  #pragma unroll
  for (int kb=0; kb<4; ++kb){
    int ka = kb*32 + q*8;
    b16x8 a[6];
    #pragma unroll
    for (int mt=0; mt<6; ++mt)
      a[mt] = *(const b16x8*)(As + (mt*16+m)*LDA + ka);
    #pragma unroll
    for (int mt=0; mt<6; ++mt)
      #pragma unroll
      for (int t=0; t<2; ++t)
        acc[mt][t] = __builtin_amdgcn_mfma_f32_16x16x32_bf16(a[mt], bfr[kb][t], acc[mt][t], 0,0,0);
  }
}

__device__ __forceinline__ void zero_acc(f32x4 acc[6][2]){
  #pragma unroll
  for (int mt=0; mt<6; ++mt)
    #pragma unroll
    for (int t=0; t<2; ++t){ acc[mt][t][0]=0.f; acc[mt][t][1]=0.f; acc[mt][t][2]=0.f; acc[mt][t][3]=0.f; }
}

__device__ __forceinline__ void epilogue_to_lds(const f32x4 acc[6][2], const float* bias, bf16* As,
                                                int lane, int w, int validRows){
  int q = lane >> 4, n = lane & 15;
  #pragma unroll
  for (int mt=0; mt<6; ++mt)
    #pragma unroll
    for (int t=0; t<2; ++t){
      int col = (w*2+t)*16 + n;
      float bc = bias[col];
      #pragma unroll
      for (int i=0; i<4; ++i){
        int row = mt*16 + q*4 + i;
        float v = (row < validRows) ? elu(acc[mt][t][i] + bc) : 0.f;
        As[row*LDA + col] = (bf16)v;
      }
    }
}

__device__ __forceinline__ void write_acc_f32(const f32x4 acc[6][2], float* out, int lane, int w){
  int q = lane >> 4, n = lane & 15;
  #pragma unroll
  for (int mt=0; mt<6; ++mt)
    #pragma unroll
    for (int t=0; t<2; ++t){
      int col = (w*2+t)*16 + n;
      #pragma unroll
      for (int i=0; i<4; ++i)
        out[(mt*16 + q*4 + i)*NH + col] = acc[mt][t][i];
    }
}

__device__ __forceinline__ void store_and_stats(const bf16* As, bf16* g_out, float* statsDst,
                                                int tid, int validRows){
  for (int i = tid; i < validRows*16; i += TB){
    int row = i >> 4, c8 = (i & 15) << 3;
    *(b16x8*)(g_out + (size_t)row*NH + c8) = *(const b16x8*)(As + row*LDA + c8);
  }
  int c = tid & 127, half = tid >> 7;
  float s = 0.f, s2 = 0.f;
  for (int row = half; row < validRows; row += 2){
    float v = (float)As[row*LDA + c];
    s += v; s2 += v*v;
  }
  atomicAdd(&statsDst[c], s);
  atomicAdd(&statsDst[128+c], s2);
}

// Build A-tile: rows = edges of 4 recv groups of 23; A = ELU(yr[r]+ys[s]+bias); pad rows 92..95 = 0
__device__ __forceinline__ void build_A(bf16* As, const float* ytr, const float* yts,
                                        const float* bias, int tile4, int tid){
  for (int i=tid; i<96*32; i+=TB){
    int row = i >> 5, c4 = (i & 31) << 2;
    b16x4 o;
    if (row < 92){
      int rl = (row>=23)+(row>=46)+(row>=69);
      int j = row - rl*23;
      int s = j + (j >= tile4 + rl);
      f32x4 vr = *(const f32x4*)(ytr + rl*NH + c4);
      f32x4 vs = *(const f32x4*)(yts + s*NH + c4);
      f32x4 bb = *(const f32x4*)(bias + c4);
      #pragma unroll
      for (int k=0; k<4; ++k) o[k] = (bf16)elu(vr[k]+vs[k]+bb[k]);
    } else {
      o[0]=o[1]=o[2]=o[3]=(bf16)0.f;
    }
    *(b16x4*)(As + row*LDA + c4) = o;
  }
}

// Register harvest: v = ELU(acc+bias) masked to valid rows. Column stats AND 4 recv-group
// column sums accumulated in REGISTERS (group index is compile-time for most (mt,i):
// row span per lane is 12 < 23, so at most one runtime boundary select), then one
// shfl_down(32)+shfl_down(16) tree per value; lane<16 writes z directly to global
// and issues one atomicAdd per stats address. NO LDS atomics (R2's 9.5M-conflict regression).
__device__ __forceinline__ void harvest(const f32x4 acc[6][2], const float* bias,
                                        float* zdst, float* statsDst, int lane, int w){
  int q4 = (lane >> 4) << 2, n = lane & 15;
  int c0 = w*32 + n, c1 = c0 + 16;
  float b0 = bias[c0], b1 = bias[c1];
  float zs0[4] = {0,0,0,0}, zs1[4] = {0,0,0,0};
  float s0=0.f, p0=0.f, s1=0.f, p1=0.f;
  #pragma unroll
  for (int mt=0; mt<6; ++mt){
    #pragma unroll
    for (int i=0; i<4; ++i){
      const int R0 = mt*16 + i;          // compile-time base row
      int row = R0 + q4;
      bool ok = row < 92;
      float v0 = elu(acc[mt][0][i] + b0); v0 = ok ? v0 : 0.f;
      float v1 = elu(acc[mt][1][i] + b1); v1 = ok ? v1 : 0.f;
      s0 += v0; p0 += v0*v0; s1 += v1; p1 += v1*v1;
      const int gLo = (R0>=23)+(R0>=46)+(R0>=69);
      const int gHi = ((R0+12)>=23)+((R0+12)>=46)+((R0+12)>=69);
      if (gLo == gHi){
        zs0[gLo] += v0; zs1[gLo] += v1;
      } else {
        const int bnd = (gHi==1) ? 23 : ((gHi==2) ? 46 : 69);
        bool hi = row >= bnd;
        zs0[gLo] += hi ? 0.f : v0;  zs0[gHi] += hi ? v0 : 0.f;
        zs1[gLo] += hi ? 0.f : v1;  zs1[gHi] += hi ? v1 : 0.f;
      }
    }
  }
  #pragma unroll
  for (int g=0; g<4; ++g){
    zs0[g] += __shfl_down(zs0[g],32); zs0[g] += __shfl_down(zs0[g],16);
    zs1[g] += __shfl_down(zs1[g],32); zs1[g] += __shfl_down(zs1[g],16);
  }
  s0 += __shfl_down(s0,32); s0 += __shfl_down(s0,16);
  p0 += __shfl_down(p0,32); p0 += __shfl_down(p0,16);
  s1 += __shfl_down(s1,32); s1 += __shfl_down(s1,16);
  p1 += __shfl_down(p1,32); p1 += __shfl_down(p1,16);
  if (lane < 16){
    #pragma unroll
    for (int g=0; g<4; ++g){
      zdst[g*NH + c0] = zs0[g];
      zdst[g*NH + c1] = zs1[g];
    }
    atomicAdd(&statsDst[c0], s0); atomicAdd(&statsDst[NH+c0], p0);
    atomicAdd(&statsDst[c1], s1); atomicAdd(&statsDst[NH+c1], p1);
  }
}

// ---- K1: MLP1 (6->128 VALU, 128->128 MFMA) -> h1 (pre-BN, bf16) + BN1 stats ----
__global__ __launch_bounds__(TB) void k1_mlp1(const float* __restrict__ in,
    const float* __restrict__ w1, const float* __restrict__ b1,
    const float* __restrict__ w2, const float* __restrict__ b2,
    bf16* __restrict__ h1, float* __restrict__ bn1){
  __shared__ alignas(16) bf16 As[96*LDA];
  __shared__ float w1s[128*6];
  __shared__ float b1s[128], b2s[128];
  __shared__ float ins[96*6];
  int tid = threadIdx.x;
  int row0 = blockIdx.x * 96;
  for (int i=tid; i<768; i+=TB) w1s[i] = w1[i];
  if (tid < 128){ b1s[tid]=b1[tid]; b2s[tid]=b2[tid]; }
  for (int i=tid; i<576; i+=TB) ins[i] = in[row0*6 + i];
  __syncthreads();
  for (int i=tid; i<96*32; i+=TB){
    int row = i >> 5, c4 = (i & 31) << 2;
    float x0=ins[row*6+0], x1=ins[row*6+1], x2=ins[row*6+2],
          x3=ins[row*6+3], x4=ins[row*6+4], x5=ins[row*6+5];
    #pragma unroll
    for (int j=0; j<4; ++j){
      int c = c4 + j;
      const float* wr = w1s + c*6;
      float s = b1s[c] + wr[0]*x0 + wr[1]*x1 + wr[2]*x2 + wr[3]*x3 + wr[4]*x4 + wr[5]*x5;
      As[row*LDA + c] = (bf16)elu(s);
    }
  }
  int lane = tid & 63, w = tid >> 6;
  b16x8 bfr[4][2];
  load_bfrags(w2, 128, 0, bfr, lane, w);
  __syncthreads();
  f32x4 acc[6][2]; zero_acc(acc);
  gemm_regB(As, bfr, acc, lane);
  __syncthreads();
  epilogue_to_lds(acc, b2s, As, lane, w, 96);
  __syncthreads();
  store_and_stats(As, h1 + (size_t)row0*NH, bn1, tid, 96);
}

// ---- K2/K4b: fold BN affine into h, project yr = W[:, :128]@x, ys = W[:,128:256]@x per node ----
__global__ __launch_bounds__(TB) void k_project(const bf16* __restrict__ hin,
    const float* __restrict__ stats, float cnt,
    const float* __restrict__ g, const float* __restrict__ be,
    const float* __restrict__ Wp, int ldw,
    float* __restrict__ yr, float* __restrict__ ys){
  __shared__ alignas(16) bf16 As[96*LDA];
  __shared__ float scl[128], shf[128];
  int tid = threadIdx.x;
  int row0 = blockIdx.x * 96;
  if (tid < 128){
    float mean = stats[tid] / cnt;
    float var  = stats[128+tid] / cnt - mean*mean;
    float rs = rsqrtf(var + EPS);
    float sc = g[tid] * rs;
    scl[tid] = sc; shf[tid] = be[tid] - mean*sc;
  }
  __syncthreads();
  for (int i=tid; i<96*16; i+=TB){
    int row = i >> 4, c8 = (i & 15) << 3;
    b16x8 v = *(const b16x8*)(hin + (size_t)(row0+row)*NH + c8);
    b16x8 o;
    #pragma unroll
    for (int j=0; j<8; ++j) o[j] = (bf16)(scl[c8+j]*(float)v[j] + shf[c8+j]);
    *(b16x8*)(As + row*LDA + c8) = o;
  }
  int lane = tid & 63, w = tid >> 6;
  b16x8 bfr[4][2];
  load_bfrags(Wp, ldw, 0, bfr, lane, w);
  __syncthreads();
  f32x4 acc[6][2]; zero_acc(acc);
  gemm_regB(As, bfr, acc, lane);
  write_acc_f32(acc, yr + (size_t)row0*NH, lane, w);
  load_bfrags(Wp, ldw, 128, bfr, lane, w);
  zero_acc(acc);
  gemm_regB(As, bfr, acc, lane);
  write_acc_f32(acc, ys + (size_t)row0*NH, lane, w);
}

// ---- K3: per-edge MLP2, NO h2 store: A=ELU(y2r[r]+y2s[s]+b21), GEMM W22, reg-harvest BN2 stats + z2 ----
__global__ __launch_bounds__(TB,3) void k3_edge1(const float* __restrict__ y2r, const float* __restrict__ y2s,
    const float* __restrict__ b21, const float* __restrict__ w22, const float* __restrict__ b22,
    float* __restrict__ z2, float* __restrict__ bn2buck){
  __shared__ alignas(16) bf16 As[96*LDA];
  __shared__ alignas(16) float ytab[3584];   // [4][128] recv rows + [24][128] send rows
  __shared__ float b1s[NH], b2s[NH];
  int tid = threadIdx.x;
  int b = blockIdx.x / 6, tile = blockIdx.x % 6, tile4 = tile*4;
  {
    const f32x4* yrB = (const f32x4*)(y2r + ((size_t)b*NK + tile4)*NH);
    const f32x4* ysB = (const f32x4*)(y2s + (size_t)b*NK*NH);
    for (int i=tid; i<896; i+=TB){
      const f32x4* p = (i < 128) ? (yrB + i) : (ysB + (i-128));
      ((f32x4*)ytab)[i] = *p;
    }
  }
  if (tid < NH){ b1s[tid]=b21[tid]; b2s[tid]=b22[tid]; }
  int lane = tid & 63, w = tid >> 6;
  b16x8 bfr[4][2];
  load_bfrags(w22, 128, 0, bfr, lane, w);
  __syncthreads();
  build_A(As, ytab, ytab+512, b1s, tile4, tid);
  __syncthreads();
  f32x4 acc[6][2]; zero_acc(acc);
  gemm_regB(As, bfr, acc, lane);
  harvest(acc, b2s, z2 + (size_t)(b*NK + tile4)*NH, bn2buck + (blockIdx.x & 31)*256, lane, w);
}

// ---- K4a: finalize BN2 from buckets; MLP3 on normalized edge2node(z2); h3 + BN3 stats; export BN2 affine ----
__global__ __launch_bounds__(TB) void k4a_mlp3(const float* __restrict__ z2,
    const float* __restrict__ bn2buck, const float* __restrict__ g2, const float* __restrict__ be2,
    const float* __restrict__ w31, const float* __restrict__ b31,
    const float* __restrict__ w32, const float* __restrict__ b32,
    bf16* __restrict__ h3, float* __restrict__ bn3, float* __restrict__ sc2out){
  __shared__ alignas(16) bf16 As[96*LDA];
  __shared__ float scl[128], shf[128], b1s[128], b2s[128];
  __shared__ float sred[256];
  int tid = threadIdx.x;
  int row0 = blockIdx.x * 96;
  {
    int c = tid & 127, part = tid >> 7;
    float s = 0.f;
    for (int i=0; i<32; ++i) s += bn2buck[i*256 + part*128 + c];
    sred[tid] = s;
  }
  if (tid < 128){ b1s[tid]=b31[tid]; b2s[tid]=b32[tid]; }
  __syncthreads();
  if (tid < 128){
    float mean = sred[tid] / (float)BEcnt;
    float var  = sred[128+tid] / (float)BEcnt - mean*mean;
    float rs = rsqrtf(var + EPS);
    float sc = g2[tid] * rs;
    float sh = be2[tid] - mean*sc;
    scl[tid] = sc * (1.f/24.f);
    shf[tid] = sh * (23.f/24.f);
    if (blockIdx.x == 0){ sc2out[tid] = sc; sc2out[128+tid] = sh; }
  }
  __syncthreads();
  for (int i=tid; i<96*32; i+=TB){
    int rl = i >> 5, c4 = (i & 31) << 2;
    f32x4 v = *(const f32x4*)(z2 + (size_t)(row0+rl)*NH + c4);
    b16x4 o;
    #pragma unroll
    for (int k=0; k<4; ++k) o[k] = (bf16)(scl[c4+k]*v[k] + shf[c4+k]);
    *(b16x4*)(As + rl*LDA + c4) = o;
  }
  int lane = tid & 63, w = tid >> 6;
  b16x8 bfr[4][2];
  load_bfrags(w31, 128, 0, bfr, lane, w);
  __syncthreads();
  f32x4 acc[6][2]; zero_acc(acc);
  gemm_regB(As, bfr, acc, lane);
  __syncthreads();
  epilogue_to_lds(acc, b1s, As, lane, w, 96);
  load_bfrags(w32, 128, 0, bfr, lane, w);
  __syncthreads();
  zero_acc(acc);
  gemm_regB(As, bfr, acc, lane);
  __syncthreads();
  epilogue_to_lds(acc, b2s, As, lane, w, 96);
  __syncthreads();
  store_and_stats(As, h3 + (size_t)row0*NH, bn3, tid, 96);
}

// ---- K5: per-edge MLP4 with h2 RECOMPUTE (no global h2): 3 GEMMs; reg-harvest BN4 stats + z4 ----
__global__ __launch_bounds__(TB,3) void k5_edge2(
    const float* __restrict__ y2r, const float* __restrict__ y2s,
    const float* __restrict__ y4r, const float* __restrict__ y4s,
    const float* __restrict__ sc2,
    const float* __restrict__ b21, const float* __restrict__ w22, const float* __restrict__ b22,
    const float* __restrict__ w41, const float* __restrict__ b41,
    const float* __restrict__ w42, const float* __restrict__ b42,
    float* __restrict__ z4, float* __restrict__ bn4buck){
  __shared__ alignas(16) bf16 As[96*LDA];
  __shared__ alignas(16) float ytab[3584];
  __shared__ float b21s[NH], b22s[NH], scl[NH], shf[NH], b41s[NH], b42s[NH];
  int tid = threadIdx.x;
  int b = blockIdx.x / 6, tile = blockIdx.x % 6, tile4 = tile*4;
  {
    const f32x4* yrB = (const f32x4*)(y2r + ((size_t)b*NK + tile4)*NH);
    const f32x4* ysB = (const f32x4*)(y2s + (size_t)b*NK*NH);
    for (int i=tid; i<896; i+=TB){
      const f32x4* p = (i < 128) ? (yrB + i) : (ysB + (i-128));
      ((f32x4*)ytab)[i] = *p;
    }
  }
  if (tid < NH){
    b21s[tid]=b21[tid]; b22s[tid]=b22[tid];
    scl[tid]=sc2[tid];  shf[tid]=sc2[NH+tid];
    b41s[tid]=b41[tid]; b42s[tid]=b42[tid];
  }
  int lane = tid & 63, w = tid >> 6;
  b16x8 bfr[4][2];
  load_bfrags(w22, 128, 0, bfr, lane, w);
  __syncthreads();
  build_A(As, ytab, ytab+512, b21s, tile4, tid);    // A2 = ELU(y2r[r]+y2s[s]+b21)
  __syncthreads();
  // prefetch y4 tables into regs (overlaps GEMM W22)
  f32x4 t4[4];
  {
    const f32x4* yrB = (const f32x4*)(y4r + ((size_t)b*NK + tile4)*NH);
    const f32x4* ysB = (const f32x4*)(y4s + (size_t)b*NK*NH);
    #pragma unroll
    for (int k2=0; k2<4; ++k2){
      int i = tid + k2*TB;
      if (i < 896){
        const f32x4* p = (i < 128) ? (yrB + i) : (ysB + (i-128));
        t4[k2] = *p;
      }
    }
  }
  f32x4 acc[6][2]; zero_acc(acc);
  gemm_regB(As, bfr, acc, lane);                    // h2 pre-act = W22 @ A2
  load_bfrags(w41, 384, 256, bfr, lane, w);         // skip third of m4_w1
  __syncthreads();                                  // all waves done reading As
  // epi1: h2n = sc2*ELU(h2+b22)+sh2 -> As
  {
    int q = lane >> 4, n = lane & 15;
    #pragma unroll
    for (int mt=0; mt<6; ++mt)
      #pragma unroll
      for (int t=0; t<2; ++t){
        int col = w*32 + t*16 + n;
        float bc = b22s[col], sc = scl[col], sh = shf[col];
        #pragma unroll
        for (int i=0; i<4; ++i){
          int row = mt*16 + q*4 + i;
          float h = elu(acc[mt][t][i] + bc);
          As[row*LDA + col] = (bf16)(sc*h + sh);
        }
      }
  }
  // stash y4 tables to LDS (ytab's y2 contents dead since build_A)
  #pragma unroll
  for (int k2=0; k2<4; ++k2){
    int i = tid + k2*TB;
    if (i < 896) ((f32x4*)ytab)[i] = t4[k2];
  }
  zero_acc(acc);
  __syncthreads();                                  // As(h2n) + ytab(y4) ready
  gemm_regB(As, bfr, acc, lane);                    // skip = W41c @ h2n
  load_bfrags(w42, 128, 0, bfr, lane, w);
  __syncthreads();                                  // done reading As(h2n)
  // epi2: A4 = ELU(skip + y4r[r] + y4s[s] + b41) -> As (pad rows zeroed)
  {
    int q4v = (lane >> 4) << 2, n = lane & 15;
    const float* ytr4 = ytab;
    const float* yts4 = ytab + 512;
    #pragma unroll
    for (int mt=0; mt<6; ++mt)
      #pragma unroll
      for (int i=0; i<4; ++i){
        int row = mt*16 + q4v + i;
        bool ok = row < 92;
        int rl = (row>=23)+(row>=46)+(row>=69);
        int j = row - rl*23;
        int s = j + (j >= tile4 + rl);
        #pragma unroll
        for (int t=0; t<2; ++t){
          int col = w*32 + t*16 + n;
          float v = 0.f;
          if (ok) v = elu(acc[mt][t][i] + ytr4[rl*NH+col] + yts4[s*NH+col] + b41s[col]);
          As[row*LDA + col] = (bf16)v;
        }
      }
  }
  zero_acc(acc);
  __syncthreads();
  gemm_regB(As, bfr, acc, lane);                    // h4 pre-act = W42 @ A4
  harvest(acc, b42s, z4 + (size_t)(b*NK + tile4)*NH, bn4buck + (blockIdx.x & 31)*256, lane, w);
}

// ---- K6: finalize BN4, apply affine to z4 sums, final 3072->2 projection ----
__global__ __launch_bounds__(TB) void k6_out(const float* __restrict__ z4,
    const float* __restrict__ bn4buck, const float* __restrict__ g4, const float* __restrict__ be4,
    const float* __restrict__ fo_w, const float* __restrict__ fo_b, float* __restrict__ out){
  __shared__ float red[512];
  __shared__ float scl[128], shf[128];
  int tid = threadIdx.x, b = blockIdx.x;
  {
    int c = tid & 127, part = tid >> 7;
    float s = 0.f;
    for (int i=0; i<32; ++i) s += bn4buck[i*256 + part*128 + c];
    red[tid] = s;
  }
  __syncthreads();
  if (tid < 128){
    float mean = red[tid] / (float)BEcnt;
    float var  = red[128+tid] / (float)BEcnt - mean*mean;
    float rs = rsqrtf(var + EPS);
    float sc = g4[tid] * rs;
    scl[tid] = sc; shf[tid] = be4[tid] - mean*sc;
  }
  __syncthreads();
  const float inv24 = 1.f/24.f, f2324 = 23.f/24.f;
  float a0 = 0.f, a1 = 0.f;
  for (int i=tid; i<3072; i+=TB){
    int c = i & 127;
    float x = scl[c]*z4[(size_t)b*3072 + i]*inv24 + shf[c]*f2324;
    a0 += x * fo_w[i];
    a1 += x * fo_w[3072 + i];
  }
  red[tid] = a0; red[256+tid] = a1;
  __syncthreads();
  for (int st=128; st>0; st>>=1){
    if (tid < st){ red[tid] += red[tid+st]; red[256+tid] += red[256+tid+st]; }
    __syncthreads();
  }
  if (tid == 0){
    out[b*2+0] = red[0] + fo_b[0];
    out[b*2+1] = red[256] + fo_b[1];
  }
}

extern "C" void kernel_launch(void* const* d_in, const int* in_sizes, int n_in,
                              void* d_out, int out_size, void* d_ws, size_t ws_size,
                              hipStream_t stream){
  (void)in_sizes; (void)n_in; (void)out_size; (void)ws_size;
  const float* inputs = (const float*)d_in[0];
  const float* fo_w  = (const float*)d_in[3];
  const float* fo_b  = (const float*)d_in[4];
  const float* m1_w1=(const float*)d_in[5];  const float* m1_b1=(const float*)d_in[6];
  const float* m1_w2=(const float*)d_in[7];  const float* m1_b2=(const float*)d_in[8];
  const float* m1_g =(const float*)d_in[9];  const float* m1_be=(const float*)d_in[10];
  const float* m2_w1=(const float*)d_in[11]; const float* m2_b1=(const float*)d_in[12];
  const float* m2_w2=(const float*)d_in[13]; const float* m2_b2=(const float*)d_in[14];
  const float* m2_g =(const float*)d_in[15]; const float* m2_be=(const float*)d_in[16];
  const float* m3_w1=(const float*)d_in[17]; const float* m3_b1=(const float*)d_in[18];
  const float* m3_w2=(const float*)d_in[19]; const float* m3_b2=(const float*)d_in[20];
  const float* m3_g =(const float*)d_in[21]; const float* m3_be=(const float*)d_in[22];
  const float* m4_w1=(const float*)d_in[23]; const float* m4_b1=(const float*)d_in[24];
  const float* m4_w2=(const float*)d_in[25]; const float* m4_b2=(const float*)d_in[26];
  const float* m4_g =(const float*)d_in[27]; const float* m4_be=(const float*)d_in[28];

  char* ws = (char*)d_ws;
  float* stats = (float*)ws;
  bf16* h1  = (bf16*)(ws + OFF_H1);
  bf16* h3  = (bf16*)(ws + OFF_H3);
  float* y2r = (float*)(ws + OFF_Y2R);
  float* y2s = (float*)(ws + OFF_Y2S);
  float* y4r = (float*)(ws + OFF_Y4R);
  float* y4s = (float*)(ws + OFF_Y4S);
  float* z2  = (float*)(ws + OFF_Z2);
  float* z4  = (float*)(ws + OFF_Z4);
  float* out = (float*)d_out;

  (void)hipMemsetAsync(d_ws, 0, STATS_BYTES, stream);
  k1_mlp1<<<256, TB, 0, stream>>>(inputs, m1_w1, m1_b1, m1_w2, m1_b2, h1, stats + S_BN1);
  k_project<<<256, TB, 0, stream>>>(h1, stats + S_BN1, (float)BNODE, m1_g, m1_be, m2_w1, 256, y2r, y2s);
  k3_edge1<<<6144, TB, 0, stream>>>(y2r, y2s, m2_b1, m2_w2, m2_b2, z2, stats + S_B2);
  k4a_mlp3<<<256, TB, 0, stream>>>(z2, stats + S_B2, m2_g, m2_be, m3_w1, m3_b1, m3_w2, m3_b2,
                                   h3, stats + S_BN3, stats + S_SC2);
  k_project<<<256, TB, 0, stream>>>(h3, stats + S_BN3, (float)BNODE, m3_g, m3_be, m4_w1, 384, y4r, y4s);
  k5_edge2<<<6144, TB, 0, stream>>>(y2r, y2s, y4r, y4s, stats + S_SC2,
                                    m2_b1, m2_w2, m2_b2, m4_w1, m4_b1, m4_w2, m4_b2,
                                    z4, stats + S_B4);
  k6_out<<<1024, TB, 0, stream>>>(z4, stats + S_B4, m4_g, m4_be, fo_w, fo_b, out);
}

// Round 5
// 448.389 us; speedup vs baseline: 2.5755x; 1.0685x over previous
//
#include <hip/hip_runtime.h>

typedef __bf16 bf16;
typedef __bf16 b16x8 __attribute__((ext_vector_type(8)));
typedef __bf16 b16x4 __attribute__((ext_vector_type(4)));
typedef float f32x4 __attribute__((ext_vector_type(4)));

#define TB 256
#define LDA 136          // LDS tile row stride (bf16): 272B/row, 16B-aligned
#define NB 1024
#define NK 24
#define NE 552
#define NH 128
#define BEcnt (NB*NE)    // 565248
#define BNODE (NB*NK)    // 24576
#define EPS 1e-5f

// ---- stats region (floats) ----
#define S_BN1 0          // [256] sum/sumsq atomics (k1)
#define S_BN3 256        // [256] (k4a)
#define S_SC2 512        // [256] BN2 affine sc/sh (k_bnred)
#define S_SC4 768        // [256] BN4 affine (k_bnred)
// ---- bf16 weight cache (elements within WBF) ----
#define WB_M1W2 0
#define WB_M2W1 16384
#define WB_M2W2 49152
#define WB_M3W1 65536
#define WB_M3W2 81920
#define WB_M4W1 98304
#define WB_M4W2 147456
#define WB_TOTAL 163840
// ---- byte offsets ----
#define OFF_WBF 4096ull
#define OFF_P2  335872ull
#define OFF_P4  (OFF_P2 + 6291456ull)
#define OFF_H1  (OFF_P4 + 6291456ull)
#define OFF_H3  (OFF_H1 + 6291456ull)
#define OFF_Y2R (OFF_H3 + 6291456ull)
#define OFF_Y2S (OFF_Y2R + 6291456ull)
#define OFF_Y4R (OFF_Y2S + 6291456ull)
#define OFF_Y4S (OFF_Y4R + 6291456ull)
#define OFF_Z2  (OFF_Y4S + 6291456ull)
#define OFF_Z4  (OFF_Z2  + 12582912ull)   // total ~76 MB

__device__ __forceinline__ float elu(float x){ return x > 0.f ? x : __expf(x) - 1.f; }

// B-fragment from bf16 row-major W: lane l holds W[n0+(l&15)][k0+(l>>4)*8+j]
__device__ __forceinline__ void load_bfrags_bf(const bf16* W, int ldw, int k0,
                                               b16x8 bfr[4][2], int lane, int w){
  int n = lane & 15, q = lane >> 4;
  #pragma unroll
  for (int kb=0; kb<4; ++kb)
    #pragma unroll
    for (int t=0; t<2; ++t)
      bfr[kb][t] = *(const b16x8*)(W + (size_t)((w*2+t)*16 + n)*ldw + k0 + kb*32 + q*8);
}

__device__ __forceinline__ void gemm_regB(const bf16* As, const b16x8 bfr[4][2], f32x4 acc[6][2], int lane){
  int m = lane & 15, q = lane >> 4;
  #pragma unroll
  for (int kb=0; kb<4; ++kb){
    int ka = kb*32 + q*8;
    b16x8 a[6];
    #pragma unroll
    for (int mt=0; mt<6; ++mt)
      a[mt] = *(const b16x8*)(As + (mt*16+m)*LDA + ka);
    #pragma unroll
    for (int mt=0; mt<6; ++mt)
      #pragma unroll
      for (int t=0; t<2; ++t)
        acc[mt][t] = __builtin_amdgcn_mfma_f32_16x16x32_bf16(a[mt], bfr[kb][t], acc[mt][t], 0,0,0);
  }
}

__device__ __forceinline__ void zero_acc(f32x4 acc[6][2]){
  #pragma unroll
  for (int mt=0; mt<6; ++mt)
    #pragma unroll
    for (int t=0; t<2; ++t){ acc[mt][t][0]=0.f; acc[mt][t][1]=0.f; acc[mt][t][2]=0.f; acc[mt][t][3]=0.f; }
}

__device__ __forceinline__ void epilogue_to_lds(const f32x4 acc[6][2], const float* bias, bf16* As,
                                                int lane, int w, int validRows){
  int q = lane >> 4, n = lane & 15;
  #pragma unroll
  for (int mt=0; mt<6; ++mt)
    #pragma unroll
    for (int t=0; t<2; ++t){
      int col = (w*2+t)*16 + n;
      float bc = bias[col];
      #pragma unroll
      for (int i=0; i<4; ++i){
        int row = mt*16 + q*4 + i;
        float v = (row < validRows) ? elu(acc[mt][t][i] + bc) : 0.f;
        As[row*LDA + col] = (bf16)v;
      }
    }
}

// write accumulator (post-BN-input projections) to global as bf16
__device__ __forceinline__ void write_acc_bf(const f32x4 acc[6][2], bf16* out, int lane, int w){
  int q = lane >> 4, n = lane & 15;
  #pragma unroll
  for (int mt=0; mt<6; ++mt)
    #pragma unroll
    for (int t=0; t<2; ++t){
      int col = (w*2+t)*16 + n;
      #pragma unroll
      for (int i=0; i<4; ++i)
        out[(size_t)(mt*16 + q*4 + i)*NH + col] = (bf16)acc[mt][t][i];
    }
}

__device__ __forceinline__ void store_and_stats(const bf16* As, bf16* g_out, float* statsDst,
                                                int tid, int validRows){
  for (int i = tid; i < validRows*16; i += TB){
    int row = i >> 4, c8 = (i & 15) << 3;
    *(b16x8*)(g_out + (size_t)row*NH + c8) = *(const b16x8*)(As + row*LDA + c8);
  }
  int c = tid & 127, half = tid >> 7;
  float s = 0.f, s2 = 0.f;
  for (int row = half; row < validRows; row += 2){
    float v = (float)As[row*LDA + c];
    s += v; s2 += v*v;
  }
  atomicAdd(&statsDst[c], s);
  atomicAdd(&statsDst[128+c], s2);
}

// Build A-tile from GLOBAL bf16 y-tables (L2-hot): rows = 4 recv groups x 23 edges; pad 92..95 = 0
__device__ __forceinline__ void build_A_g(bf16* As, const bf16* yrG, const bf16* ysG,
                                          const float* bias, int tile4, int tid){
  for (int i=tid; i<96*16; i+=TB){
    int row = i >> 4, c8 = (i & 15) << 3;
    b16x8 o;
    if (row < 92){
      int rl = (row>=23)+(row>=46)+(row>=69);
      int j = row - rl*23;
      int s = j + (j >= tile4 + rl);
      b16x8 vr = *(const b16x8*)(yrG + (size_t)rl*NH + c8);
      b16x8 vs = *(const b16x8*)(ysG + (size_t)s*NH + c8);
      #pragma unroll
      for (int k=0; k<8; ++k) o[k] = (bf16)elu((float)vr[k] + (float)vs[k] + bias[c8+k]);
    } else {
      #pragma unroll
      for (int k=0; k<8; ++k) o[k] = (bf16)0.f;
    }
    *(b16x8*)(As + row*LDA + c8) = o;
  }
}

// Register harvest: ELU(acc+bias), per-column stats + 4 recv-group sums in registers,
// shfl_down(32/16) tree, lane<16 plain-stores z (global) and per-block stats partials.
__device__ __forceinline__ void harvest(const f32x4 acc[6][2], const float* bias,
                                        float* zdst, float* pdst, int lane, int w){
  int q4 = (lane >> 4) << 2, n = lane & 15;
  int c0 = w*32 + n, c1 = c0 + 16;
  float b0 = bias[c0], b1 = bias[c1];
  float zs0[4] = {0,0,0,0}, zs1[4] = {0,0,0,0};
  float s0=0.f, p0=0.f, s1=0.f, p1=0.f;
  #pragma unroll
  for (int mt=0; mt<6; ++mt){
    #pragma unroll
    for (int i=0; i<4; ++i){
      const int R0 = mt*16 + i;
      int row = R0 + q4;
      bool ok = row < 92;
      float v0 = elu(acc[mt][0][i] + b0); v0 = ok ? v0 : 0.f;
      float v1 = elu(acc[mt][1][i] + b1); v1 = ok ? v1 : 0.f;
      s0 += v0; p0 += v0*v0; s1 += v1; p1 += v1*v1;
      const int gLo = (R0>=23)+(R0>=46)+(R0>=69);
      const int gHi = ((R0+12)>=23)+((R0+12)>=46)+((R0+12)>=69);
      if (gLo == gHi){
        zs0[gLo] += v0; zs1[gLo] += v1;
      } else {
        const int bnd = (gHi==1) ? 23 : ((gHi==2) ? 46 : 69);
        bool hi = row >= bnd;
        zs0[gLo] += hi ? 0.f : v0;  zs0[gHi] += hi ? v0 : 0.f;
        zs1[gLo] += hi ? 0.f : v1;  zs1[gHi] += hi ? v1 : 0.f;
      }
    }
  }
  #pragma unroll
  for (int g=0; g<4; ++g){
    zs0[g] += __shfl_down(zs0[g],32); zs0[g] += __shfl_down(zs0[g],16);
    zs1[g] += __shfl_down(zs1[g],32); zs1[g] += __shfl_down(zs1[g],16);
  }
  s0 += __shfl_down(s0,32); s0 += __shfl_down(s0,16);
  p0 += __shfl_down(p0,32); p0 += __shfl_down(p0,16);
  s1 += __shfl_down(s1,32); s1 += __shfl_down(s1,16);
  p1 += __shfl_down(p1,32); p1 += __shfl_down(p1,16);
  if (lane < 16){
    #pragma unroll
    for (int g=0; g<4; ++g){
      zdst[g*NH + c0] = zs0[g];
      zdst[g*NH + c1] = zs1[g];
    }
    pdst[c0] = s0; pdst[128+c0] = p0;
    pdst[c1] = s1; pdst[128+c1] = p1;
  }
}

// ---- K0: one-time fp32 -> bf16 weight conversion into ws ----
__global__ __launch_bounds__(TB) void k0_cvt(const float* __restrict__ s0, const float* __restrict__ s1,
    const float* __restrict__ s2, const float* __restrict__ s3, const float* __restrict__ s4,
    const float* __restrict__ s5, const float* __restrict__ s6, bf16* __restrict__ dst){
  int idx = (blockIdx.x*TB + threadIdx.x)*4;
  const float* sp; int base;
  if      (idx < 16384){ sp=s0; base=0; }
  else if (idx < 49152){ sp=s1; base=16384; }
  else if (idx < 65536){ sp=s2; base=49152; }
  else if (idx < 81920){ sp=s3; base=65536; }
  else if (idx < 98304){ sp=s4; base=81920; }
  else if (idx <147456){ sp=s5; base=98304; }
  else                 { sp=s6; base=147456; }
  f32x4 v = *(const f32x4*)(sp + (idx - base));
  b16x4 o; o[0]=(bf16)v[0]; o[1]=(bf16)v[1]; o[2]=(bf16)v[2]; o[3]=(bf16)v[3];
  *(b16x4*)(dst + idx) = o;
}

// ---- K1: MLP1 (6->128 VALU, 128->128 MFMA) -> h1 (pre-BN bf16) + BN1 stats ----
__global__ __launch_bounds__(TB) void k1_mlp1(const float* __restrict__ in,
    const float* __restrict__ w1, const float* __restrict__ b1,
    const bf16* __restrict__ w2, const float* __restrict__ b2,
    bf16* __restrict__ h1, float* __restrict__ bn1){
  __shared__ alignas(16) bf16 As[96*LDA];
  __shared__ float w1s[128*6];
  __shared__ float b1s[128], b2s[128];
  __shared__ float ins[96*6];
  int tid = threadIdx.x;
  int row0 = blockIdx.x * 96;
  for (int i=tid; i<768; i+=TB) w1s[i] = w1[i];
  if (tid < 128){ b1s[tid]=b1[tid]; b2s[tid]=b2[tid]; }
  for (int i=tid; i<576; i+=TB) ins[i] = in[row0*6 + i];
  __syncthreads();
  for (int i=tid; i<96*32; i+=TB){
    int row = i >> 5, c4 = (i & 31) << 2;
    float x0=ins[row*6+0], x1=ins[row*6+1], x2=ins[row*6+2],
          x3=ins[row*6+3], x4=ins[row*6+4], x5=ins[row*6+5];
    #pragma unroll
    for (int j=0; j<4; ++j){
      int c = c4 + j;
      const float* wr = w1s + c*6;
      float s = b1s[c] + wr[0]*x0 + wr[1]*x1 + wr[2]*x2 + wr[3]*x3 + wr[4]*x4 + wr[5]*x5;
      As[row*LDA + c] = (bf16)elu(s);
    }
  }
  int lane = tid & 63, w = tid >> 6;
  b16x8 bfr[4][2];
  load_bfrags_bf(w2, 128, 0, bfr, lane, w);
  __syncthreads();
  f32x4 acc[6][2]; zero_acc(acc);
  gemm_regB(As, bfr, acc, lane);
  __syncthreads();
  epilogue_to_lds(acc, b2s, As, lane, w, 96);
  __syncthreads();
  store_and_stats(As, h1 + (size_t)row0*NH, bn1, tid, 96);
}

// ---- K2/K4b: fold BN affine into h, project yr=W[:,:128]@x, ys=W[:,128:256]@x -> bf16 ----
__global__ __launch_bounds__(TB) void k_project(const bf16* __restrict__ hin,
    const float* __restrict__ stats, float cnt,
    const float* __restrict__ g, const float* __restrict__ be,
    const bf16* __restrict__ Wp, int ldw,
    bf16* __restrict__ yr, bf16* __restrict__ ys){
  __shared__ alignas(16) bf16 As[96*LDA];
  __shared__ float scl[128], shf[128];
  int tid = threadIdx.x;
  int row0 = blockIdx.x * 96;
  if (tid < 128){
    float mean = stats[tid] / cnt;
    float var  = stats[128+tid] / cnt - mean*mean;
    float rs = rsqrtf(var + EPS);
    float sc = g[tid] * rs;
    scl[tid] = sc; shf[tid] = be[tid] - mean*sc;
  }
  __syncthreads();
  for (int i=tid; i<96*16; i+=TB){
    int row = i >> 4, c8 = (i & 15) << 3;
    b16x8 v = *(const b16x8*)(hin + (size_t)(row0+row)*NH + c8);
    b16x8 o;
    #pragma unroll
    for (int j=0; j<8; ++j) o[j] = (bf16)(scl[c8+j]*(float)v[j] + shf[c8+j]);
    *(b16x8*)(As + row*LDA + c8) = o;
  }
  int lane = tid & 63, w = tid >> 6;
  b16x8 bfr[4][2];
  load_bfrags_bf(Wp, ldw, 0, bfr, lane, w);
  __syncthreads();
  f32x4 acc[6][2]; zero_acc(acc);
  gemm_regB(As, bfr, acc, lane);
  write_acc_bf(acc, yr + (size_t)row0*NH, lane, w);
  load_bfrags_bf(Wp, ldw, 128, bfr, lane, w);
  zero_acc(acc);
  gemm_regB(As, bfr, acc, lane);
  write_acc_bf(acc, ys + (size_t)row0*NH, lane, w);
}

// ---- K3: per-edge MLP2, no h2 store: A=ELU(y2r[r]+y2s[s]+b21) from global bf16 tables,
//      GEMM W22(bf16), reg-harvest -> z2 + per-block stats partials ----
__global__ __launch_bounds__(TB,5) void k3_edge1(const bf16* __restrict__ y2r, const bf16* __restrict__ y2s,
    const float* __restrict__ b21, const bf16* __restrict__ w22, const float* __restrict__ b22,
    float* __restrict__ z2, float* __restrict__ P2){
  __shared__ alignas(16) bf16 As[96*LDA];
  __shared__ float b1s[NH], b2s[NH];
  int tid = threadIdx.x;
  int b = blockIdx.x / 6, tile = blockIdx.x % 6, tile4 = tile*4;
  if (tid < NH){ b1s[tid]=b21[tid]; b2s[tid]=b22[tid]; }
  int lane = tid & 63, w = tid >> 6;
  b16x8 bfr[4][2];
  load_bfrags_bf(w22, 128, 0, bfr, lane, w);
  __syncthreads();
  build_A_g(As, y2r + ((size_t)b*NK + tile4)*NH, y2s + (size_t)b*NK*NH, b1s, tile4, tid);
  __syncthreads();
  f32x4 acc[6][2]; zero_acc(acc);
  gemm_regB(As, bfr, acc, lane);
  harvest(acc, b2s, z2 + (size_t)(b*NK + tile4)*NH, P2 + (size_t)blockIdx.x*256, lane, w);
}

// ---- K3b/K5b: reduce P[6144][256] -> BN affine (sc[128], sh[128]); 8 blocks x 16 cols ----
__global__ __launch_bounds__(TB) void k_bnred(const float* __restrict__ P,
    const float* __restrict__ g, const float* __restrict__ be, float* __restrict__ aff){
  __shared__ float rs[256], rq[256];
  int tid = threadIdx.x;
  int col = blockIdx.x*16 + (tid & 15);   // col in [0,128)
  int chunk = tid >> 4;
  const float* p0 = P + (size_t)chunk*384*256 + col;
  float s=0.f, q=0.f;
  for (int r=0; r<384; ++r){
    s += p0[(size_t)r*256];
    q += p0[(size_t)r*256 + 128];
  }
  rs[tid]=s; rq[tid]=q;
  __syncthreads();
  if (tid < 16){
    float S=0.f, Q=0.f;
    #pragma unroll
    for (int c2=0; c2<16; ++c2){ S += rs[c2*16+tid]; Q += rq[c2*16+tid]; }
    int cc = blockIdx.x*16 + tid;
    float mean = S / (float)BEcnt;
    float var  = Q / (float)BEcnt - mean*mean;
    float sc = g[cc] * rsqrtf(var + EPS);
    aff[cc] = sc; aff[128+cc] = be[cc] - mean*sc;
  }
}

// ---- K4a: MLP3 on normalized edge2node(z2) using BN2 affine; h3 + BN3 stats ----
__global__ __launch_bounds__(TB) void k4a_mlp3(const float* __restrict__ z2,
    const float* __restrict__ aff2,
    const bf16* __restrict__ w31, const float* __restrict__ b31,
    const bf16* __restrict__ w32, const float* __restrict__ b32,
    bf16* __restrict__ h3, float* __restrict__ bn3){
  __shared__ alignas(16) bf16 As[96*LDA];
  __shared__ float scl[128], shf[128], b1s[128], b2s[128];
  int tid = threadIdx.x;
  int row0 = blockIdx.x * 96;
  if (tid < 128){
    scl[tid] = aff2[tid] * (1.f/24.f);
    shf[tid] = aff2[128+tid] * (23.f/24.f);
    b1s[tid] = b31[tid]; b2s[tid] = b32[tid];
  }
  __syncthreads();
  for (int i=tid; i<96*32; i+=TB){
    int rl = i >> 5, c4 = (i & 31) << 2;
    f32x4 v = *(const f32x4*)(z2 + (size_t)(row0+rl)*NH + c4);
    b16x4 o;
    #pragma unroll
    for (int k=0; k<4; ++k) o[k] = (bf16)(scl[c4+k]*v[k] + shf[c4+k]);
    *(b16x4*)(As + rl*LDA + c4) = o;
  }
  int lane = tid & 63, w = tid >> 6;
  b16x8 bfr[4][2];
  load_bfrags_bf(w31, 128, 0, bfr, lane, w);
  __syncthreads();
  f32x4 acc[6][2]; zero_acc(acc);
  gemm_regB(As, bfr, acc, lane);
  __syncthreads();
  epilogue_to_lds(acc, b1s, As, lane, w, 96);
  load_bfrags_bf(w32, 128, 0, bfr, lane, w);
  __syncthreads();
  zero_acc(acc);
  gemm_regB(As, bfr, acc, lane);
  __syncthreads();
  epilogue_to_lds(acc, b2s, As, lane, w, 96);
  __syncthreads();
  store_and_stats(As, h3 + (size_t)row0*NH, bn3, tid, 96);
}

// ---- K5: per-edge MLP4 with h2 recompute: 3 GEMMs; reg-harvest -> z4 + stats partials ----
__global__ __launch_bounds__(TB,4) void k5_edge2(
    const bf16* __restrict__ y2r, const bf16* __restrict__ y2s,
    const bf16* __restrict__ y4r, const bf16* __restrict__ y4s,
    const float* __restrict__ aff2,
    const float* __restrict__ b21, const bf16* __restrict__ w22, const float* __restrict__ b22,
    const bf16* __restrict__ w41, const float* __restrict__ b41,
    const bf16* __restrict__ w42, const float* __restrict__ b42,
    float* __restrict__ z4, float* __restrict__ P4){
  __shared__ alignas(16) bf16 As[96*LDA];
  __shared__ alignas(16) bf16 yt4[28*LDA];   // rows 0-3: y4r slice, rows 4-27: y4s
  __shared__ float b21s[NH], b22s[NH], scl[NH], shf[NH], b41s[NH], b42s[NH];
  int tid = threadIdx.x;
  int b = blockIdx.x / 6, tile = blockIdx.x % 6, tile4 = tile*4;
  if (tid < NH){
    b21s[tid]=b21[tid]; b22s[tid]=b22[tid];
    scl[tid]=aff2[tid]; shf[tid]=aff2[NH+tid];
    b41s[tid]=b41[tid]; b42s[tid]=b42[tid];
  }
  int lane = tid & 63, w = tid >> 6;
  b16x8 bfr[4][2];
  load_bfrags_bf(w22, 128, 0, bfr, lane, w);
  __syncthreads();
  build_A_g(As, y2r + ((size_t)b*NK + tile4)*NH, y2s + (size_t)b*NK*NH, b21s, tile4, tid);
  {  // stage y4 tables (bf16) into LDS for epi2's scattered reads
    const bf16* y4rG = y4r + ((size_t)b*NK + tile4)*NH;
    const bf16* y4sG = y4s + (size_t)b*NK*NH;
    for (int i=tid; i<448; i+=TB){
      int r = i >> 4, c8 = (i & 15) << 3;
      b16x8 v = (r < 4) ? *(const b16x8*)(y4rG + (size_t)r*NH + c8)
                        : *(const b16x8*)(y4sG + (size_t)(r-4)*NH + c8);
      *(b16x8*)(yt4 + r*LDA + c8) = v;
    }
  }
  __syncthreads();
  f32x4 acc[6][2]; zero_acc(acc);
  gemm_regB(As, bfr, acc, lane);                    // h2 pre-act = W22 @ A2
  load_bfrags_bf(w41, 384, 256, bfr, lane, w);      // skip third of m4_w1
  __syncthreads();                                  // all waves done reading As
  // epi1: h2n = sc2*ELU(h2+b22)+sh2 -> As
  {
    int q = lane >> 4, n = lane & 15;
    #pragma unroll
    for (int mt=0; mt<6; ++mt)
      #pragma unroll
      for (int t=0; t<2; ++t){
        int col = w*32 + t*16 + n;
        float bc = b22s[col], sc = scl[col], sh = shf[col];
        #pragma unroll
        for (int i=0; i<4; ++i){
          int row = mt*16 + q*4 + i;
          float h = elu(acc[mt][t][i] + bc);
          As[row*LDA + col] = (bf16)(sc*h + sh);
        }
      }
  }
  zero_acc(acc);
  __syncthreads();                                  // As(h2n) ready
  gemm_regB(As, bfr, acc, lane);                    // skip = W41c @ h2n
  load_bfrags_bf(w42, 128, 0, bfr, lane, w);
  __syncthreads();                                  // done reading As(h2n)
  // epi2: A4 = ELU(skip + y4r[r] + y4s[s] + b41) -> As (pad rows zeroed)
  {
    int q4v = (lane >> 4) << 2, n = lane & 15;
    #pragma unroll
    for (int mt=0; mt<6; ++mt)
      #pragma unroll
      for (int i=0; i<4; ++i){
        int row = mt*16 + q4v + i;
        bool ok = row < 92;
        int rl = (row>=23)+(row>=46)+(row>=69);
        int j = row - rl*23;
        int s = j + (j >= tile4 + rl);
        #pragma unroll
        for (int t=0; t<2; ++t){
          int col = w*32 + t*16 + n;
          float v = 0.f;
          if (ok) v = elu(acc[mt][t][i] + (float)yt4[rl*LDA+col] + (float)yt4[(4+s)*LDA+col] + b41s[col]);
          As[row*LDA + col] = (bf16)v;
        }
      }
  }
  zero_acc(acc);
  __syncthreads();
  gemm_regB(As, bfr, acc, lane);                    // h4 pre-act = W42 @ A4
  harvest(acc, b42s, z4 + (size_t)(b*NK + tile4)*NH, P4 + (size_t)blockIdx.x*256, lane, w);
}

// ---- K6: apply BN4 affine to z4 sums, final 3072->2 projection ----
__global__ __launch_bounds__(TB) void k6_out(const float* __restrict__ z4,
    const float* __restrict__ aff4,
    const float* __restrict__ fo_w, const float* __restrict__ fo_b, float* __restrict__ out){
  __shared__ float red[512];
  __shared__ float scl[128], shf[128];
  int tid = threadIdx.x, b = blockIdx.x;
  if (tid < 128){ scl[tid] = aff4[tid]; shf[tid] = aff4[128+tid]; }
  __syncthreads();
  const float inv24 = 1.f/24.f, f2324 = 23.f/24.f;
  float a0 = 0.f, a1 = 0.f;
  for (int i=tid; i<3072; i+=TB){
    int c = i & 127;
    float x = scl[c]*z4[(size_t)b*3072 + i]*inv24 + shf[c]*f2324;
    a0 += x * fo_w[i];
    a1 += x * fo_w[3072 + i];
  }
  red[tid] = a0; red[256+tid] = a1;
  __syncthreads();
  for (int st=128; st>0; st>>=1){
    if (tid < st){ red[tid] += red[tid+st]; red[256+tid] += red[256+tid+st]; }
    __syncthreads();
  }
  if (tid == 0){
    out[b*2+0] = red[0] + fo_b[0];
    out[b*2+1] = red[256] + fo_b[1];
  }
}

extern "C" void kernel_launch(void* const* d_in, const int* in_sizes, int n_in,
                              void* d_out, int out_size, void* d_ws, size_t ws_size,
                              hipStream_t stream){
  (void)in_sizes; (void)n_in; (void)out_size; (void)ws_size;
  const float* inputs = (const float*)d_in[0];
  const float* fo_w  = (const float*)d_in[3];
  const float* fo_b  = (const float*)d_in[4];
  const float* m1_w1=(const float*)d_in[5];  const float* m1_b1=(const float*)d_in[6];
  const float* m1_w2=(const float*)d_in[7];  const float* m1_b2=(const float*)d_in[8];
  const float* m1_g =(const float*)d_in[9];  const float* m1_be=(const float*)d_in[10];
  const float* m2_w1=(const float*)d_in[11]; const float* m2_b1=(const float*)d_in[12];
  const float* m2_w2=(const float*)d_in[13]; const float* m2_b2=(const float*)d_in[14];
  const float* m2_g =(const float*)d_in[15]; const float* m2_be=(const float*)d_in[16];
  const float* m3_w1=(const float*)d_in[17]; const float* m3_b1=(const float*)d_in[18];
  const float* m3_w2=(const float*)d_in[19]; const float* m3_b2=(const float*)d_in[20];
  const float* m3_g =(const float*)d_in[21]; const float* m3_be=(const float*)d_in[22];
  const float* m4_w1=(const float*)d_in[23]; const float* m4_b1=(const float*)d_in[24];
  const float* m4_w2=(const float*)d_in[25]; const float* m4_b2=(const float*)d_in[26];
  const float* m4_g =(const float*)d_in[27]; const float* m4_be=(const float*)d_in[28];

  char* ws = (char*)d_ws;
  float* stats = (float*)ws;
  bf16* wbf = (bf16*)(ws + OFF_WBF);
  float* P2 = (float*)(ws + OFF_P2);
  float* P4 = (float*)(ws + OFF_P4);
  bf16* h1  = (bf16*)(ws + OFF_H1);
  bf16* h3  = (bf16*)(ws + OFF_H3);
  bf16* y2r = (bf16*)(ws + OFF_Y2R);
  bf16* y2s = (bf16*)(ws + OFF_Y2S);
  bf16* y4r = (bf16*)(ws + OFF_Y4R);
  bf16* y4s = (bf16*)(ws + OFF_Y4S);
  float* z2  = (float*)(ws + OFF_Z2);
  float* z4  = (float*)(ws + OFF_Z4);
  float* out = (float*)d_out;

  (void)hipMemsetAsync(d_ws, 0, 2048, stream);   // bn1/bn3 atomic accumulators only
  k0_cvt<<<160, TB, 0, stream>>>(m1_w2, m2_w1, m2_w2, m3_w1, m3_w2, m4_w1, m4_w2, wbf);
  k1_mlp1<<<256, TB, 0, stream>>>(inputs, m1_w1, m1_b1, wbf + WB_M1W2, m1_b2, h1, stats + S_BN1);
  k_project<<<256, TB, 0, stream>>>(h1, stats + S_BN1, (float)BNODE, m1_g, m1_be,
                                    wbf + WB_M2W1, 256, y2r, y2s);
  k3_edge1<<<6144, TB, 0, stream>>>(y2r, y2s, m2_b1, wbf + WB_M2W2, m2_b2, z2, P2);
  k_bnred<<<8, TB, 0, stream>>>(P2, m2_g, m2_be, stats + S_SC2);
  k4a_mlp3<<<256, TB, 0, stream>>>(z2, stats + S_SC2, wbf + WB_M3W1, m3_b1,
                                   wbf + WB_M3W2, m3_b2, h3, stats + S_BN3);
  k_project<<<256, TB, 0, stream>>>(h3, stats + S_BN3, (float)BNODE, m3_g, m3_be,
                                    wbf + WB_M4W1, 384, y4r, y4s);
  k5_edge2<<<6144, TB, 0, stream>>>(y2r, y2s, y4r, y4s, stats + S_SC2,
                                    m2_b1, wbf + WB_M2W2, m2_b2,
                                    wbf + WB_M4W1, m4_b1, wbf + WB_M4W2, m4_b2,
                                    z4, P4);
  k_bnred<<<8, TB, 0, stream>>>(P4, m4_g, m4_be, stats + S_SC4);
  k6_out<<<1024, TB, 0, stream>>>(z4, stats + S_SC4, fo_w, fo_b, out);
}